// Round 1
// baseline (681.112 us; speedup 1.0000x reference)
//
#include <hip/hip_runtime.h>

#define N_ASSETS 4096
#define DMODEL 512
#define DKQ 128
#define NUM_EMB 1024

typedef float f32x4 __attribute__((ext_vector_type(4)));
typedef short s16x8 __attribute__((ext_vector_type(8)));

__device__ __forceinline__ unsigned short f2bf(float x) {
    unsigned u = __float_as_uint(x);
    u += 0x7FFF + ((u >> 16) & 1);
    return (unsigned short)(u >> 16);
}

__device__ __forceinline__ s16x8 ld8(const unsigned short* p) {
    return *(const s16x8*)p;
}

// ---------------- K0: gate table: sigmoid(rank_emb @ wL + b) [1024] ----------------
__global__ void k_gate(const float* __restrict__ remb, const float* __restrict__ wLw,
                       const float* __restrict__ wLb, float* __restrict__ gate) {
    int e = blockIdx.x * 256 + threadIdx.x;
    if (e < NUM_EMB) {
        float s = wLb[0];
#pragma unroll
        for (int j = 0; j < 32; ++j) s += remb[e * 32 + j] * wLw[j];
        gate[e] = 1.f / (1.f + __expf(-s));
    }
}

// ---------------- K1: X fp32 -> bf16 ----------------
__global__ void k_convx(const float* __restrict__ X, unsigned short* __restrict__ Xb, int n) {
    int i4 = (blockIdx.x * 256 + threadIdx.x) * 4;
    if (i4 < n) {
        float4 v = *(const float4*)(X + i4);
        ushort4 o;
        o.x = f2bf(v.x); o.y = f2bf(v.y); o.z = f2bf(v.z); o.w = f2bf(v.w);
        *(ushort4*)(Xb + i4) = o;
    }
}

// ---------------- K2: combined W [768][512] fp32 -> bf16, plus combined bias ----------------
__global__ void k_convw(const float* __restrict__ Wq, const float* __restrict__ Wk,
                        const float* __restrict__ Wv, const float* __restrict__ bq,
                        const float* __restrict__ bk, const float* __restrict__ bv,
                        unsigned short* __restrict__ Wb, float* __restrict__ bias) {
    int gid = blockIdx.x * 256 + threadIdx.x;
    int i4 = gid * 4;
    if (i4 < 768 * 512) {
        int row = i4 >> 9;
        int col = i4 & 511;
        const float* src; int r;
        if (row < 128)      { src = Wq; r = row; }
        else if (row < 256) { src = Wk; r = row - 128; }
        else                { src = Wv; r = row - 256; }
        float4 v = *(const float4*)(src + r * 512 + col);
        ushort4 o;
        o.x = f2bf(v.x); o.y = f2bf(v.y); o.z = f2bf(v.z); o.w = f2bf(v.w);
        *(ushort4*)(Wb + i4) = o;
    }
    if (gid < 768) {
        float b;
        if (gid < 128)      b = bq[gid];
        else if (gid < 256) b = bk[gid - 128];
        else                b = bv[gid - 256];
        bias[gid] = b;
    }
}

// ---------------- K3: QKV projection: C[4096][768] = Xb @ Wb^T + bias ----------------
// bt-GEMM, 16x16x32 bf16 MFMA, block = 4 waves, block tile 64(M)x64(N), no LDS.
__global__ __launch_bounds__(256) void k_qkv(const unsigned short* __restrict__ Xb,
                                             const unsigned short* __restrict__ Wb,
                                             const float* __restrict__ bias,
                                             unsigned short* __restrict__ qb,
                                             unsigned short* __restrict__ kb,
                                             unsigned short* __restrict__ vb) {
    int tid = threadIdx.x;
    int lane = tid & 63, w = tid >> 6;
    int l15 = lane & 15, lhi = lane >> 4;
    int m0 = blockIdx.x * 64 + w * 16;
    int n0 = blockIdx.y * 64;

    f32x4 zero4 = {0.f, 0.f, 0.f, 0.f};
    f32x4 acc[4];
#pragma unroll
    for (int s = 0; s < 4; ++s) acc[s] = zero4;

    const unsigned short* arow = Xb + (m0 + l15) * 512 + lhi * 8;
    for (int k0 = 0; k0 < 512; k0 += 32) {
        s16x8 af = ld8(arow + k0);
#pragma unroll
        for (int s = 0; s < 4; ++s) {
            s16x8 bf = ld8(Wb + (n0 + 16 * s + l15) * 512 + k0 + lhi * 8);
            acc[s] = __builtin_amdgcn_mfma_f32_16x16x32_bf16(af, bf, acc[s], 0, 0, 0);
        }
    }
#pragma unroll
    for (int s = 0; s < 4; ++s) {
        int n = n0 + 16 * s + l15;
        float bv_ = bias[n];
#pragma unroll
        for (int r = 0; r < 4; ++r) {
            int m = m0 + lhi * 4 + r;
            unsigned short val = f2bf(acc[s][r] + bv_);
            if (n < 128)      qb[m * 128 + n] = val;
            else if (n < 256) kb[m * 128 + (n - 128)] = val;
            else              vb[m * 512 + (n - 256)] = val;
        }
    }
}

// ---------------- K4: transpose vb [4096][512] -> vt [512][4096] (bf16) ----------------
__global__ __launch_bounds__(256) void k_transp(const unsigned short* __restrict__ vb,
                                                unsigned short* __restrict__ vt) {
    __shared__ unsigned short tl[64][72];  // row stride 144B: 16B-aligned writes
    int tid = threadIdx.x;
    int m0 = blockIdx.x * 64, d0 = blockIdx.y * 64;
    int r = tid >> 2, c16 = (tid & 3) * 16;
    const unsigned short* src = vb + (m0 + r) * 512 + d0 + c16;
    *(s16x8*)&tl[r][c16] = ld8(src);
    *(s16x8*)&tl[r][c16 + 8] = ld8(src + 8);
    __syncthreads();
    int dd = tid >> 2, m16 = (tid & 3) * 16;
    s16x8 o0, o1;
#pragma unroll
    for (int j = 0; j < 8; ++j) {
        o0[j] = (short)tl[m16 + j][dd];
        o1[j] = (short)tl[m16 + 8 + j][dd];
    }
    unsigned short* dst = vt + (d0 + dd) * 4096 + m0 + m16;
    *(s16x8*)dst = o0;
    *(s16x8*)(dst + 8) = o1;
}

// ---------------- K5: flash attention with psi gate ----------------
// 256 blocks x 1 wave; 16 q-rows per wave; CB=32 column steps; online softmax
// with defer-max (THR=8); PV accumulates a[16][512] in 32 f32x4 acc frags.
__global__ __launch_bounds__(64, 1) void k_attn(const unsigned short* __restrict__ qb,
                                                const unsigned short* __restrict__ kb,
                                                const unsigned short* __restrict__ vt,
                                                const float* __restrict__ ranks,
                                                const float* __restrict__ gate,
                                                float* __restrict__ aout) {
    __shared__ float r_lds[N_ASSETS];
    __shared__ float g_lds[NUM_EMB];
    __shared__ unsigned short p_lds[16 * 40];  // 16 rows x 32 cols, pad to 40

    int lane = threadIdx.x;
    int l15 = lane & 15, lhi = lane >> 4;
    int r0 = blockIdx.x * 16;

    for (int i = lane; i < N_ASSETS; i += 64) r_lds[i] = ranks[i];
    for (int i = lane; i < NUM_EMB; i += 64) g_lds[i] = gate[i];
    __syncthreads();

    // Q fragments: A-operand rows r0..r0+15, K=128 in 4 chunks of 32
    s16x8 aq[4];
#pragma unroll
    for (int kc = 0; kc < 4; ++kc) aq[kc] = ld8(qb + (r0 + l15) * DKQ + kc * 32 + lhi * 8);

    // ranks of this lane's 4 output rows
    float ri[4];
#pragma unroll
    for (int r = 0; r < 4; ++r) ri[r] = r_lds[r0 + lhi * 4 + r];

    float mrun[4], lsum[4];
#pragma unroll
    for (int r = 0; r < 4; ++r) { mrun[r] = -1e30f; lsum[r] = 0.f; }

    f32x4 zero4 = {0.f, 0.f, 0.f, 0.f};
    f32x4 acc[32];
#pragma unroll
    for (int s = 0; s < 32; ++s) acc[s] = zero4;

    const float scale = 0.08838834764831845f;  // 1/sqrt(128)

    for (int c0 = 0; c0 < N_ASSETS; c0 += 32) {
        float sv[2][4];
#pragma unroll
        for (int t = 0; t < 2; ++t) {
            f32x4 sacc = zero4;
            int c = c0 + 16 * t + l15;  // this lane's key index (acc col = l15)
            const unsigned short* kp = kb + c * DKQ + lhi * 8;
#pragma unroll
            for (int kc = 0; kc < 4; ++kc)
                sacc = __builtin_amdgcn_mfma_f32_16x16x32_bf16(aq[kc], ld8(kp + kc * 32), sacc, 0, 0, 0);
            float rj = r_lds[c];
#pragma unroll
            for (int r = 0; r < 4; ++r) {
                float diff = fabsf(ri[r] - rj);
                int d = (int)(diff * 0.25f);
                d = min(d, NUM_EMB - 1);
                sv[t][r] = sacc[r] * scale * g_lds[d];
            }
        }
        // per-row tile max (reduce across the 16-lane col group)
        float tm[4];
#pragma unroll
        for (int r = 0; r < 4; ++r) {
            float v = fmaxf(sv[0][r], sv[1][r]);
            v = fmaxf(v, __shfl_xor(v, 1));
            v = fmaxf(v, __shfl_xor(v, 2));
            v = fmaxf(v, __shfl_xor(v, 4));
            v = fmaxf(v, __shfl_xor(v, 8));
            tm[r] = v;
        }
        bool need = false;
#pragma unroll
        for (int r = 0; r < 4; ++r) need = need || (tm[r] > mrun[r] + 8.f);
        if (__any((int)need)) {
#pragma unroll
            for (int r = 0; r < 4; ++r) {
                float mn = fmaxf(mrun[r], tm[r]);
                float al = __expf(mrun[r] - mn);
                mrun[r] = mn;
                lsum[r] *= al;
#pragma unroll
                for (int s = 0; s < 32; ++s) acc[s][r] *= al;
            }
        }
        // P = exp(S - m), accumulate per-lane l, stage P tile to LDS (bf16)
#pragma unroll
        for (int t = 0; t < 2; ++t) {
#pragma unroll
            for (int r = 0; r < 4; ++r) {
                float p = __expf(sv[t][r] - mrun[r]);
                lsum[r] += p;
                p_lds[(lhi * 4 + r) * 40 + 16 * t + l15] = f2bf(p);
            }
        }
        __syncthreads();
        // A-frag of P: m = l15, k = lhi*8+e
        s16x8 pa = *(const s16x8*)&p_lds[l15 * 40 + lhi * 8];
        // PV: B-frag from Vt (bt layout): n = s*16+l15, k = c0 + lhi*8 + e
        const unsigned short* vp = vt + l15 * 4096 + c0 + lhi * 8;
#pragma unroll
        for (int s = 0; s < 32; ++s) {
            acc[s] = __builtin_amdgcn_mfma_f32_16x16x32_bf16(pa, ld8(vp + s * 16 * 4096), acc[s], 0, 0, 0);
        }
        __syncthreads();
    }

    // finalize l (reduce per-lane partial sums across the 16-lane col group)
#pragma unroll
    for (int r = 0; r < 4; ++r) {
        float v = lsum[r];
        v += __shfl_xor(v, 1);
        v += __shfl_xor(v, 2);
        v += __shfl_xor(v, 4);
        v += __shfl_xor(v, 8);
        lsum[r] = v;
    }
#pragma unroll
    for (int s = 0; s < 32; ++s) {
#pragma unroll
        for (int r = 0; r < 4; ++r) {
            int row = r0 + lhi * 4 + r;
            aout[row * 512 + s * 16 + l15] = acc[s][r] / lsum[r];
        }
    }
}

// ---------------- K6: out = sigmoid(a @ wf + b) ----------------
__global__ __launch_bounds__(256) void k_out(const float* __restrict__ a,
                                             const float* __restrict__ wfw,
                                             const float* __restrict__ wfb,
                                             float* __restrict__ out) {
    int lane = threadIdx.x & 63, w = threadIdx.x >> 6;
    int row = blockIdx.x * 4 + w;
    const float4* ap = (const float4*)(a + row * 512 + lane * 8);
    const float4* wp = (const float4*)(wfw + lane * 8);
    float4 a0 = ap[0], a1 = ap[1], w0 = wp[0], w1 = wp[1];
    float s = a0.x * w0.x + a0.y * w0.y + a0.z * w0.z + a0.w * w0.w
            + a1.x * w1.x + a1.y * w1.y + a1.z * w1.z + a1.w * w1.w;
#pragma unroll
    for (int m = 1; m < 64; m <<= 1) s += __shfl_xor(s, m);
    if (lane == 0) out[row] = 1.f / (1.f + __expf(-(s + wfb[0])));
}

extern "C" void kernel_launch(void* const* d_in, const int* in_sizes, int n_in,
                              void* d_out, int out_size, void* d_ws, size_t ws_size,
                              hipStream_t stream) {
    const float* X    = (const float*)d_in[0];
    const float* rks  = (const float*)d_in[1];
    const float* Wq_w = (const float*)d_in[2];
    const float* Wq_b = (const float*)d_in[3];
    const float* Wk_w = (const float*)d_in[4];
    const float* Wk_b = (const float*)d_in[5];
    const float* Wv_w = (const float*)d_in[6];
    const float* Wv_b = (const float*)d_in[7];
    const float* remb = (const float*)d_in[8];
    const float* wL_w = (const float*)d_in[9];
    const float* wL_b = (const float*)d_in[10];
    const float* wf_w = (const float*)d_in[11];
    const float* wf_b = (const float*)d_in[12];
    float* out = (float*)d_out;
    char* ws = (char*)d_ws;

    const size_t OFF_GATE = 0;                       // 1024 f32
    const size_t OFF_BIAS = 4096;                    // 768 f32
    const size_t OFF_XB   = 8192;                    // 4096x512 bf16
    const size_t OFF_WB   = OFF_XB + 4194304;        // 768x512 bf16
    const size_t OFF_QB   = OFF_WB + 786432;         // 4096x128 bf16
    const size_t OFF_KB   = OFF_QB + 1048576;        // 4096x128 bf16
    const size_t OFF_VB   = OFF_KB + 1048576;        // 4096x512 bf16
    const size_t OFF_VT   = OFF_VB + 4194304;        // 512x4096 bf16
    const size_t OFF_A    = OFF_VT + 4194304;        // 4096x512 f32

    float* gate = (float*)(ws + OFF_GATE);
    float* bias = (float*)(ws + OFF_BIAS);
    unsigned short* Xb = (unsigned short*)(ws + OFF_XB);
    unsigned short* Wb = (unsigned short*)(ws + OFF_WB);
    unsigned short* qb = (unsigned short*)(ws + OFF_QB);
    unsigned short* kb = (unsigned short*)(ws + OFF_KB);
    unsigned short* vb = (unsigned short*)(ws + OFF_VB);
    unsigned short* vt = (unsigned short*)(ws + OFF_VT);
    float* aout = (float*)(ws + OFF_A);

    k_gate<<<4, 256, 0, stream>>>(remb, wL_w, wL_b, gate);
    k_convx<<<2048, 256, 0, stream>>>(X, Xb, N_ASSETS * DMODEL);
    k_convw<<<384, 256, 0, stream>>>(Wq_w, Wk_w, Wv_w, Wq_b, Wk_b, Wv_b, Wb, bias);
    k_qkv<<<dim3(64, 12), 256, 0, stream>>>(Xb, Wb, bias, qb, kb, vb);
    k_transp<<<dim3(64, 8), 256, 0, stream>>>(vb, vt);
    k_attn<<<256, 64, 0, stream>>>(qb, kb, vt, rks, gate, aout);
    k_out<<<1024, 256, 0, stream>>>(aout, wf_w, wf_b, out);
}

// Round 2
// 196.868 us; speedup vs baseline: 3.4597x; 3.4597x over previous
//
#include <hip/hip_runtime.h>

#define N_ASSETS 4096
#define DMODEL 512
#define DKQ 128
#define NUM_EMB 1024

typedef float f32x4 __attribute__((ext_vector_type(4)));
typedef short s16x8 __attribute__((ext_vector_type(8)));

__device__ __forceinline__ unsigned short f2bf(float x) {
    unsigned u = __float_as_uint(x);
    u += 0x7FFF + ((u >> 16) & 1);
    return (unsigned short)(u >> 16);
}

__device__ __forceinline__ float bf2f(unsigned short x) {
    return __uint_as_float((unsigned)x << 16);
}

__device__ __forceinline__ s16x8 ld8(const unsigned short* p) {
    return *(const s16x8*)p;
}

// ---------------- K0: gate table: sigmoid(rank_emb @ wL + b) [1024] ----------------
__global__ void k_gate(const float* __restrict__ remb, const float* __restrict__ wLw,
                       const float* __restrict__ wLb, float* __restrict__ gate) {
    int e = blockIdx.x * 256 + threadIdx.x;
    if (e < NUM_EMB) {
        float s = wLb[0];
#pragma unroll
        for (int j = 0; j < 32; ++j) s += remb[e * 32 + j] * wLw[j];
        gate[e] = 1.f / (1.f + __expf(-s));
    }
}

// ---------------- K1: X fp32 -> bf16 ----------------
__global__ void k_convx(const float* __restrict__ X, unsigned short* __restrict__ Xb, int n) {
    int i4 = (blockIdx.x * 256 + threadIdx.x) * 4;
    if (i4 < n) {
        float4 v = *(const float4*)(X + i4);
        ushort4 o;
        o.x = f2bf(v.x); o.y = f2bf(v.y); o.z = f2bf(v.z); o.w = f2bf(v.w);
        *(ushort4*)(Xb + i4) = o;
    }
}

// ---------------- K2: combined W [768][512] fp32 -> bf16, plus combined bias ----------------
__global__ void k_convw(const float* __restrict__ Wq, const float* __restrict__ Wk,
                        const float* __restrict__ Wv, const float* __restrict__ bq,
                        const float* __restrict__ bk, const float* __restrict__ bv,
                        unsigned short* __restrict__ Wb, float* __restrict__ bias) {
    int gid = blockIdx.x * 256 + threadIdx.x;
    int i4 = gid * 4;
    if (i4 < 768 * 512) {
        int row = i4 >> 9;
        int col = i4 & 511;
        const float* src; int r;
        if (row < 128)      { src = Wq; r = row; }
        else if (row < 256) { src = Wk; r = row - 128; }
        else                { src = Wv; r = row - 256; }
        float4 v = *(const float4*)(src + r * 512 + col);
        ushort4 o;
        o.x = f2bf(v.x); o.y = f2bf(v.y); o.z = f2bf(v.z); o.w = f2bf(v.w);
        *(ushort4*)(Wb + i4) = o;
    }
    if (gid < 768) {
        float b;
        if (gid < 128)      b = bq[gid];
        else if (gid < 256) b = bk[gid - 128];
        else                b = bv[gid - 256];
        bias[gid] = b;
    }
}

// ---------------- K3: QKV projection: C[4096][768] = Xb @ Wb^T + bias ----------------
__global__ __launch_bounds__(256) void k_qkv(const unsigned short* __restrict__ Xb,
                                             const unsigned short* __restrict__ Wb,
                                             const float* __restrict__ bias,
                                             unsigned short* __restrict__ qb,
                                             unsigned short* __restrict__ kb,
                                             unsigned short* __restrict__ vb) {
    int tid = threadIdx.x;
    int lane = tid & 63, w = tid >> 6;
    int l15 = lane & 15, lhi = lane >> 4;
    int m0 = blockIdx.x * 64 + w * 16;
    int n0 = blockIdx.y * 64;

    f32x4 zero4 = {0.f, 0.f, 0.f, 0.f};
    f32x4 acc[4];
#pragma unroll
    for (int s = 0; s < 4; ++s) acc[s] = zero4;

    const unsigned short* arow = Xb + (m0 + l15) * 512 + lhi * 8;
    for (int k0 = 0; k0 < 512; k0 += 32) {
        s16x8 af = ld8(arow + k0);
#pragma unroll
        for (int s = 0; s < 4; ++s) {
            s16x8 bf = ld8(Wb + (n0 + 16 * s + l15) * 512 + k0 + lhi * 8);
            acc[s] = __builtin_amdgcn_mfma_f32_16x16x32_bf16(af, bf, acc[s], 0, 0, 0);
        }
    }
#pragma unroll
    for (int s = 0; s < 4; ++s) {
        int n = n0 + 16 * s + l15;
        float bv_ = bias[n];
#pragma unroll
        for (int r = 0; r < 4; ++r) {
            int m = m0 + lhi * 4 + r;
            unsigned short val = f2bf(acc[s][r] + bv_);
            if (n < 128)      qb[m * 128 + n] = val;
            else if (n < 256) kb[m * 128 + (n - 128)] = val;
            else              vb[m * 512 + (n - 256)] = val;
        }
    }
}

// ---------------- K4: transpose vb [4096][512] -> vt [512][4096] (bf16) ----------------
__global__ __launch_bounds__(256) void k_transp(const unsigned short* __restrict__ vb,
                                                unsigned short* __restrict__ vt) {
    __shared__ unsigned short tl[64][72];
    int tid = threadIdx.x;
    int m0 = blockIdx.x * 64, d0 = blockIdx.y * 64;
    int r = tid >> 2, c16 = (tid & 3) * 16;
    const unsigned short* src = vb + (m0 + r) * 512 + d0 + c16;
    *(s16x8*)&tl[r][c16] = ld8(src);
    *(s16x8*)&tl[r][c16 + 8] = ld8(src + 8);
    __syncthreads();
    int dd = tid >> 2, m16 = (tid & 3) * 16;
    s16x8 o0, o1;
#pragma unroll
    for (int j = 0; j < 8; ++j) {
        o0[j] = (short)tl[m16 + j][dd];
        o1[j] = (short)tl[m16 + 8 + j][dd];
    }
    unsigned short* dst = vt + (d0 + dd) * 4096 + m0 + m16;
    *(s16x8*)dst = o0;
    *(s16x8*)(dst + 8) = o1;
}

// ---------------- K5: P = exp(psi * (Q K^T) / sqrt(dk))  [4096][4096] bf16 ----------------
// 128x128 tile per block, 4 waves (2x2), each wave 64x64. Grid 32x32 = 1024 blocks.
// Also writes per-(colblock-half, row) partial row sums (deterministic slots).
__global__ __launch_bounds__(256) void k_score(const unsigned short* __restrict__ qb,
                                               const unsigned short* __restrict__ kb,
                                               const float* __restrict__ ranks,
                                               const float* __restrict__ gate,
                                               unsigned short* __restrict__ P,
                                               float* __restrict__ rs_part) {
    __shared__ float g_lds[NUM_EMB];
    __shared__ float rr[128], rc[128];
    int tid = threadIdx.x;
    int lane = tid & 63, w = tid >> 6;
    int l15 = lane & 15, lhi = lane >> 4;
    int wm = w >> 1, wn = w & 1;
    int bm = blockIdx.x, bn = blockIdx.y;

    for (int i = tid; i < NUM_EMB; i += 256) g_lds[i] = gate[i];
    if (tid < 128) {
        rr[tid] = ranks[bm * 128 + tid];
        rc[tid] = ranks[bn * 128 + tid];
    }
    __syncthreads();

    int row0 = wm * 64;  // local within block tile
    int col0 = wn * 64;

    f32x4 zero4 = {0.f, 0.f, 0.f, 0.f};
    f32x4 acc[4][4];
#pragma unroll
    for (int mi = 0; mi < 4; ++mi)
#pragma unroll
        for (int ni = 0; ni < 4; ++ni) acc[mi][ni] = zero4;

#pragma unroll
    for (int k0 = 0; k0 < DKQ; k0 += 32) {
        s16x8 af[4], bf[4];
#pragma unroll
        for (int mi = 0; mi < 4; ++mi)
            af[mi] = ld8(qb + (bm * 128 + row0 + mi * 16 + l15) * DKQ + k0 + lhi * 8);
#pragma unroll
        for (int ni = 0; ni < 4; ++ni)
            bf[ni] = ld8(kb + (bn * 128 + col0 + ni * 16 + l15) * DKQ + k0 + lhi * 8);
#pragma unroll
        for (int mi = 0; mi < 4; ++mi)
#pragma unroll
            for (int ni = 0; ni < 4; ++ni)
                acc[mi][ni] = __builtin_amdgcn_mfma_f32_16x16x32_bf16(af[mi], bf[ni], acc[mi][ni], 0, 0, 0);
    }

    const float scale = 0.08838834764831845f;  // 1/sqrt(128)
    float rs[4][4];
#pragma unroll
    for (int mi = 0; mi < 4; ++mi)
#pragma unroll
        for (int r = 0; r < 4; ++r) rs[mi][r] = 0.f;

#pragma unroll
    for (int mi = 0; mi < 4; ++mi) {
#pragma unroll
        for (int ni = 0; ni < 4; ++ni) {
            int coll = col0 + ni * 16 + l15;
            float rj = rc[coll];
#pragma unroll
            for (int r = 0; r < 4; ++r) {
                int rowl = row0 + mi * 16 + lhi * 4 + r;
                float s = acc[mi][ni][r] * scale;
                float diff = fabsf(rr[rowl] - rj);
                int d = min((int)(diff * 0.25f), NUM_EMB - 1);
                float p = __expf(g_lds[d] * s);
                unsigned short us = f2bf(p);
                P[(size_t)(bm * 128 + rowl) * N_ASSETS + bn * 128 + coll] = us;
                rs[mi][r] += bf2f(us);
            }
        }
    }
#pragma unroll
    for (int mi = 0; mi < 4; ++mi) {
#pragma unroll
        for (int r = 0; r < 4; ++r) {
            float v = rs[mi][r];
            v += __shfl_xor(v, 1);
            v += __shfl_xor(v, 2);
            v += __shfl_xor(v, 4);
            v += __shfl_xor(v, 8);
            if (l15 == 0) {
                int row = bm * 128 + row0 + mi * 16 + lhi * 4 + r;
                rs_part[(bn * 2 + wn) * N_ASSETS + row] = v;
            }
        }
    }
}

// ---------------- K6: A_unnorm[4096][512] = P @ V  (B^T = vt) ----------------
// 64x64 tile, 4 waves (2x2), each wave 32x32 (acc[2][2]). Grid 64x8 = 512 blocks.
__global__ __launch_bounds__(256) void k_pv(const unsigned short* __restrict__ P,
                                            const unsigned short* __restrict__ vt,
                                            float* __restrict__ Aout) {
    int tid = threadIdx.x;
    int lane = tid & 63, w = tid >> 6;
    int l15 = lane & 15, lhi = lane >> 4;
    int wm = w >> 1, wn = w & 1;
    int m0 = blockIdx.x * 64 + wm * 32;
    int n0 = blockIdx.y * 64 + wn * 32;

    f32x4 zero4 = {0.f, 0.f, 0.f, 0.f};
    f32x4 acc[2][2];
#pragma unroll
    for (int mi = 0; mi < 2; ++mi)
#pragma unroll
        for (int ni = 0; ni < 2; ++ni) acc[mi][ni] = zero4;

    const unsigned short* pa = P + (size_t)(m0 + l15) * N_ASSETS + lhi * 8;
    const unsigned short* pb = vt + (size_t)(n0 + l15) * N_ASSETS + lhi * 8;

    for (int k0 = 0; k0 < N_ASSETS; k0 += 32) {
        s16x8 af[2], bf[2];
#pragma unroll
        for (int mi = 0; mi < 2; ++mi) af[mi] = ld8(pa + (size_t)mi * 16 * N_ASSETS + k0);
#pragma unroll
        for (int ni = 0; ni < 2; ++ni) bf[ni] = ld8(pb + (size_t)ni * 16 * N_ASSETS + k0);
#pragma unroll
        for (int mi = 0; mi < 2; ++mi)
#pragma unroll
            for (int ni = 0; ni < 2; ++ni)
                acc[mi][ni] = __builtin_amdgcn_mfma_f32_16x16x32_bf16(af[mi], bf[ni], acc[mi][ni], 0, 0, 0);
    }
#pragma unroll
    for (int mi = 0; mi < 2; ++mi)
#pragma unroll
        for (int ni = 0; ni < 2; ++ni)
#pragma unroll
            for (int r = 0; r < 4; ++r)
                Aout[(m0 + mi * 16 + lhi * 4 + r) * DMODEL + n0 + ni * 16 + l15] = acc[mi][ni][r];
}

// ---------------- K7: out = sigmoid((A . wf)/l + b) ----------------
__global__ __launch_bounds__(256) void k_out(const float* __restrict__ a,
                                             const float* __restrict__ rs_part,
                                             const float* __restrict__ wfw,
                                             const float* __restrict__ wfb,
                                             float* __restrict__ out) {
    int lane = threadIdx.x & 63, w = threadIdx.x >> 6;
    int row = blockIdx.x * 4 + w;
    const float4* ap = (const float4*)(a + row * 512 + lane * 8);
    const float4* wp = (const float4*)(wfw + lane * 8);
    float4 a0 = ap[0], a1 = ap[1], w0 = wp[0], w1 = wp[1];
    float s = a0.x * w0.x + a0.y * w0.y + a0.z * w0.z + a0.w * w0.w
            + a1.x * w1.x + a1.y * w1.y + a1.z * w1.z + a1.w * w1.w;
    float lp = rs_part[lane * N_ASSETS + row];
#pragma unroll
    for (int m = 1; m < 64; m <<= 1) {
        s += __shfl_xor(s, m);
        lp += __shfl_xor(lp, m);
    }
    if (lane == 0) out[row] = 1.f / (1.f + __expf(-(s / lp + wfb[0])));
}

extern "C" void kernel_launch(void* const* d_in, const int* in_sizes, int n_in,
                              void* d_out, int out_size, void* d_ws, size_t ws_size,
                              hipStream_t stream) {
    const float* X    = (const float*)d_in[0];
    const float* rks  = (const float*)d_in[1];
    const float* Wq_w = (const float*)d_in[2];
    const float* Wq_b = (const float*)d_in[3];
    const float* Wk_w = (const float*)d_in[4];
    const float* Wk_b = (const float*)d_in[5];
    const float* Wv_w = (const float*)d_in[6];
    const float* Wv_b = (const float*)d_in[7];
    const float* remb = (const float*)d_in[8];
    const float* wL_w = (const float*)d_in[9];
    const float* wL_b = (const float*)d_in[10];
    const float* wf_w = (const float*)d_in[11];
    const float* wf_b = (const float*)d_in[12];
    float* out = (float*)d_out;
    char* ws = (char*)d_ws;

    const size_t OFF_GATE = 0;                        // 1024 f32
    const size_t OFF_BIAS = 4096;                     // 768 f32 (pad 4KB)
    const size_t OFF_XB   = 8192;                     // 4096x512 bf16 (4MB)
    const size_t OFF_WB   = OFF_XB + 4194304;         // 768x512 bf16 (0.75MB)
    const size_t OFF_QB   = OFF_WB + 786432;          // 4096x128 bf16 (1MB)
    const size_t OFF_KB   = OFF_QB + 1048576;         // 4096x128 bf16 (1MB)
    const size_t OFF_VB   = OFF_KB + 1048576;         // 4096x512 bf16 (4MB)
    const size_t OFF_VT   = OFF_VB + 4194304;         // 512x4096 bf16 (4MB)
    const size_t OFF_A    = OFF_VT + 4194304;         // 4096x512 f32 (8MB)
    const size_t OFF_P    = OFF_A + 8388608;          // 4096x4096 bf16 (32MB)
    const size_t OFF_RS   = OFF_P + 33554432;         // 64x4096 f32 (1MB)

    float* gate = (float*)(ws + OFF_GATE);
    float* bias = (float*)(ws + OFF_BIAS);
    unsigned short* Xb = (unsigned short*)(ws + OFF_XB);
    unsigned short* Wb = (unsigned short*)(ws + OFF_WB);
    unsigned short* qb = (unsigned short*)(ws + OFF_QB);
    unsigned short* kb = (unsigned short*)(ws + OFF_KB);
    unsigned short* vb = (unsigned short*)(ws + OFF_VB);
    unsigned short* vt = (unsigned short*)(ws + OFF_VT);
    float* aout = (float*)(ws + OFF_A);
    unsigned short* P = (unsigned short*)(ws + OFF_P);
    float* rs_part = (float*)(ws + OFF_RS);

    k_gate<<<4, 256, 0, stream>>>(remb, wL_w, wL_b, gate);
    k_convx<<<2048, 256, 0, stream>>>(X, Xb, N_ASSETS * DMODEL);
    k_convw<<<384, 256, 0, stream>>>(Wq_w, Wk_w, Wv_w, Wq_b, Wk_b, Wv_b, Wb, bias);
    k_qkv<<<dim3(64, 12), 256, 0, stream>>>(Xb, Wb, bias, qb, kb, vb);
    k_transp<<<dim3(64, 8), 256, 0, stream>>>(vb, vt);
    k_score<<<dim3(32, 32), 256, 0, stream>>>(qb, kb, rks, gate, P, rs_part);
    k_pv<<<dim3(64, 8), 256, 0, stream>>>(P, vt, aout);
    k_out<<<1024, 256, 0, stream>>>(aout, rs_part, wf_w, wf_b, out);
}

// Round 3
// 115.459 us; speedup vs baseline: 5.8992x; 1.7051x over previous
//
#include <hip/hip_runtime.h>

#define N_ASSETS 4096
#define DMODEL 512
#define DKQ 128
#define NUM_EMB 1024

typedef float f32x4 __attribute__((ext_vector_type(4)));
typedef short s16x8 __attribute__((ext_vector_type(8)));

__device__ __forceinline__ unsigned short f2bf(float x) {
    unsigned u = __float_as_uint(x);
    u += 0x7FFF + ((u >> 16) & 1);
    return (unsigned short)(u >> 16);
}

__device__ __forceinline__ float bf2f(unsigned short x) {
    return __uint_as_float((unsigned)x << 16);
}

__device__ __forceinline__ s16x8 ld8(const unsigned short* p) {
    return *(const s16x8*)p;
}

__device__ __forceinline__ void gload_lds16(const unsigned short* g, unsigned short* l) {
    __builtin_amdgcn_global_load_lds((const __attribute__((address_space(1))) void*)g,
                                     (__attribute__((address_space(3))) void*)l, 16, 0, 0);
}

// ---------------- K0: gate table: sigmoid(rank_emb @ wL + b) [1024] ----------------
__global__ void k_gate(const float* __restrict__ remb, const float* __restrict__ wLw,
                       const float* __restrict__ wLb, float* __restrict__ gate) {
    int e = blockIdx.x * 256 + threadIdx.x;
    if (e < NUM_EMB) {
        float s = wLb[0];
#pragma unroll
        for (int j = 0; j < 32; ++j) s += remb[e * 32 + j] * wLw[j];
        gate[e] = 1.f / (1.f + __expf(-s));
    }
}

// ---------------- K1: X fp32 -> bf16 ----------------
__global__ void k_convx(const float* __restrict__ X, unsigned short* __restrict__ Xb, int n) {
    int i4 = (blockIdx.x * 256 + threadIdx.x) * 4;
    if (i4 < n) {
        float4 v = *(const float4*)(X + i4);
        ushort4 o;
        o.x = f2bf(v.x); o.y = f2bf(v.y); o.z = f2bf(v.z); o.w = f2bf(v.w);
        *(ushort4*)(Xb + i4) = o;
    }
}

// ---------------- K2: combined W [768][512] fp32 -> bf16, plus combined bias ----------------
__global__ void k_convw(const float* __restrict__ Wq, const float* __restrict__ Wk,
                        const float* __restrict__ Wv, const float* __restrict__ bq,
                        const float* __restrict__ bk, const float* __restrict__ bv,
                        unsigned short* __restrict__ Wb, float* __restrict__ bias) {
    int gid = blockIdx.x * 256 + threadIdx.x;
    int i4 = gid * 4;
    if (i4 < 768 * 512) {
        int row = i4 >> 9;
        int col = i4 & 511;
        const float* src; int r;
        if (row < 128)      { src = Wq; r = row; }
        else if (row < 256) { src = Wk; r = row - 128; }
        else                { src = Wv; r = row - 256; }
        float4 v = *(const float4*)(src + r * 512 + col);
        ushort4 o;
        o.x = f2bf(v.x); o.y = f2bf(v.y); o.z = f2bf(v.z); o.w = f2bf(v.w);
        *(ushort4*)(Wb + i4) = o;
    }
    if (gid < 768) {
        float b;
        if (gid < 128)      b = bq[gid];
        else if (gid < 256) b = bk[gid - 128];
        else                b = bv[gid - 256];
        bias[gid] = b;
    }
}

// ---------------- K3: QKV projection: C[4096][768] = Xb @ Wb^T + bias ----------------
__global__ __launch_bounds__(256) void k_qkv(const unsigned short* __restrict__ Xb,
                                             const unsigned short* __restrict__ Wb,
                                             const float* __restrict__ bias,
                                             unsigned short* __restrict__ qb,
                                             unsigned short* __restrict__ kb,
                                             unsigned short* __restrict__ vb) {
    int tid = threadIdx.x;
    int lane = tid & 63, w = tid >> 6;
    int l15 = lane & 15, lhi = lane >> 4;
    int m0 = blockIdx.x * 64 + w * 16;
    int n0 = blockIdx.y * 64;

    f32x4 zero4 = {0.f, 0.f, 0.f, 0.f};
    f32x4 acc[4];
#pragma unroll
    for (int s = 0; s < 4; ++s) acc[s] = zero4;

    const unsigned short* arow = Xb + (m0 + l15) * 512 + lhi * 8;
    for (int k0 = 0; k0 < 512; k0 += 32) {
        s16x8 af = ld8(arow + k0);
#pragma unroll
        for (int s = 0; s < 4; ++s) {
            s16x8 bf = ld8(Wb + (n0 + 16 * s + l15) * 512 + k0 + lhi * 8);
            acc[s] = __builtin_amdgcn_mfma_f32_16x16x32_bf16(af, bf, acc[s], 0, 0, 0);
        }
    }
#pragma unroll
    for (int s = 0; s < 4; ++s) {
        int n = n0 + 16 * s + l15;
        float bv_ = bias[n];
#pragma unroll
        for (int r = 0; r < 4; ++r) {
            int m = m0 + lhi * 4 + r;
            unsigned short val = f2bf(acc[s][r] + bv_);
            if (n < 128)      qb[m * 128 + n] = val;
            else if (n < 256) kb[m * 128 + (n - 128)] = val;
            else              vb[m * 512 + (n - 256)] = val;
        }
    }
}

// ---------------- K4: transpose vb [4096][512] -> vt [512][4096] (bf16) ----------------
__global__ __launch_bounds__(256) void k_transp(const unsigned short* __restrict__ vb,
                                                unsigned short* __restrict__ vt) {
    __shared__ unsigned short tl[64][72];
    int tid = threadIdx.x;
    int m0 = blockIdx.x * 64, d0 = blockIdx.y * 64;
    int r = tid >> 2, c16 = (tid & 3) * 16;
    const unsigned short* src = vb + (m0 + r) * 512 + d0 + c16;
    *(s16x8*)&tl[r][c16] = ld8(src);
    *(s16x8*)&tl[r][c16 + 8] = ld8(src + 8);
    __syncthreads();
    int dd = tid >> 2, m16 = (tid & 3) * 16;
    s16x8 o0, o1;
#pragma unroll
    for (int j = 0; j < 8; ++j) {
        o0[j] = (short)tl[m16 + j][dd];
        o1[j] = (short)tl[m16 + 8 + j][dd];
    }
    unsigned short* dst = vt + (d0 + dd) * 4096 + m0 + m16;
    *(s16x8*)dst = o0;
    *(s16x8*)(dst + 8) = o1;
}

// ---------------- K5: P = exp(psi * (Q K^T) / sqrt(dk))  [4096][4096] bf16 ----------------
__global__ __launch_bounds__(256) void k_score(const unsigned short* __restrict__ qb,
                                               const unsigned short* __restrict__ kb,
                                               const float* __restrict__ ranks,
                                               const float* __restrict__ gate,
                                               unsigned short* __restrict__ P,
                                               float* __restrict__ rs_part) {
    __shared__ float g_lds[NUM_EMB];
    __shared__ float rr[128], rc[128];
    int tid = threadIdx.x;
    int lane = tid & 63, w = tid >> 6;
    int l15 = lane & 15, lhi = lane >> 4;
    int wm = w >> 1, wn = w & 1;
    int bm = blockIdx.x, bn = blockIdx.y;

    for (int i = tid; i < NUM_EMB; i += 256) g_lds[i] = gate[i];
    if (tid < 128) {
        rr[tid] = ranks[bm * 128 + tid];
        rc[tid] = ranks[bn * 128 + tid];
    }
    __syncthreads();

    int row0 = wm * 64;
    int col0 = wn * 64;

    f32x4 zero4 = {0.f, 0.f, 0.f, 0.f};
    f32x4 acc[4][4];
#pragma unroll
    for (int mi = 0; mi < 4; ++mi)
#pragma unroll
        for (int ni = 0; ni < 4; ++ni) acc[mi][ni] = zero4;

#pragma unroll
    for (int k0 = 0; k0 < DKQ; k0 += 32) {
        s16x8 af[4], bf[4];
#pragma unroll
        for (int mi = 0; mi < 4; ++mi)
            af[mi] = ld8(qb + (bm * 128 + row0 + mi * 16 + l15) * DKQ + k0 + lhi * 8);
#pragma unroll
        for (int ni = 0; ni < 4; ++ni)
            bf[ni] = ld8(kb + (bn * 128 + col0 + ni * 16 + l15) * DKQ + k0 + lhi * 8);
#pragma unroll
        for (int mi = 0; mi < 4; ++mi)
#pragma unroll
            for (int ni = 0; ni < 4; ++ni)
                acc[mi][ni] = __builtin_amdgcn_mfma_f32_16x16x32_bf16(af[mi], bf[ni], acc[mi][ni], 0, 0, 0);
    }

    const float scale = 0.08838834764831845f;  // 1/sqrt(128)
    float rs[4][4];
#pragma unroll
    for (int mi = 0; mi < 4; ++mi)
#pragma unroll
        for (int r = 0; r < 4; ++r) rs[mi][r] = 0.f;

#pragma unroll
    for (int mi = 0; mi < 4; ++mi) {
#pragma unroll
        for (int ni = 0; ni < 4; ++ni) {
            int coll = col0 + ni * 16 + l15;
            float rj = rc[coll];
#pragma unroll
            for (int r = 0; r < 4; ++r) {
                int rowl = row0 + mi * 16 + lhi * 4 + r;
                float s = acc[mi][ni][r] * scale;
                float diff = fabsf(rr[rowl] - rj);
                int d = min((int)(diff * 0.25f), NUM_EMB - 1);
                float p = __expf(g_lds[d] * s);
                unsigned short us = f2bf(p);
                P[(size_t)(bm * 128 + rowl) * N_ASSETS + bn * 128 + coll] = us;
                rs[mi][r] += bf2f(us);
            }
        }
    }
#pragma unroll
    for (int mi = 0; mi < 4; ++mi) {
#pragma unroll
        for (int r = 0; r < 4; ++r) {
            float v = rs[mi][r];
            v += __shfl_xor(v, 1);
            v += __shfl_xor(v, 2);
            v += __shfl_xor(v, 4);
            v += __shfl_xor(v, 8);
            if (l15 == 0) {
                int row = bm * 128 + row0 + mi * 16 + lhi * 4 + r;
                rs_part[(bn * 2 + wn) * N_ASSETS + row] = v;
            }
        }
    }
}

// ---------------- K6: partial A[z] = P[:, z-chunk] @ V[z-chunk, :]  ----------------
// m97 structure: 128x128 tile, 4 waves (2x2, each 64x64, acc 4x4), BK=32,
// double-buffered LDS via global_load_lds(16B). Split-K=4 (deterministic:
// separate partial buffers). Grid (32, 4, 4) = 512 blocks, 2 blocks/CU.
#define PV_KCHUNK 1024
#define PV_NITER (PV_KCHUNK / 32)
__global__ __launch_bounds__(256, 2) void k_pv(const unsigned short* __restrict__ P,
                                               const unsigned short* __restrict__ vt,
                                               float* __restrict__ Apart) {
    __shared__ __align__(16) unsigned short sA[2][128 * 32];
    __shared__ __align__(16) unsigned short sB[2][128 * 32];

    int tid = threadIdx.x;
    int lane = tid & 63, w = tid >> 6;
    int l15 = lane & 15, lhi = lane >> 4;
    int wm = w >> 1, wn = w & 1;
    int m0 = blockIdx.x * 128, n0 = blockIdx.y * 128;
    int kbase = blockIdx.z * PV_KCHUNK;
    float* Aout = Apart + (size_t)blockIdx.z * (N_ASSETS * DMODEL);

    // staging addresses: thread tid covers row (tid>>2) [+64], 8-elem slot (tid&3)
    const unsigned short* gA0 = P + (size_t)(m0 + (tid >> 2)) * N_ASSETS + kbase + (tid & 3) * 8;
    const unsigned short* gA1 = gA0 + (size_t)64 * N_ASSETS;
    const unsigned short* gB0 = vt + (size_t)(n0 + (tid >> 2)) * N_ASSETS + kbase + (tid & 3) * 8;
    const unsigned short* gB1 = gB0 + (size_t)64 * N_ASSETS;

#define PV_STAGE(buf, koff)                                   \
    do {                                                      \
        gload_lds16(gA0 + (koff), &sA[buf][tid * 8]);         \
        gload_lds16(gA1 + (koff), &sA[buf][2048 + tid * 8]);  \
        gload_lds16(gB0 + (koff), &sB[buf][tid * 8]);         \
        gload_lds16(gB1 + (koff), &sB[buf][2048 + tid * 8]);  \
    } while (0)

    f32x4 zero4 = {0.f, 0.f, 0.f, 0.f};
    f32x4 acc[4][4];
#pragma unroll
    for (int mi = 0; mi < 4; ++mi)
#pragma unroll
        for (int ni = 0; ni < 4; ++ni) acc[mi][ni] = zero4;

    PV_STAGE(0, 0);
    __syncthreads();

    for (int kk = 0; kk < PV_NITER; ++kk) {
        int cur = kk & 1;
        if (kk + 1 < PV_NITER) PV_STAGE(cur ^ 1, (kk + 1) * 32);

        s16x8 af[4], bf[4];
#pragma unroll
        for (int mi = 0; mi < 4; ++mi)
            af[mi] = *(const s16x8*)&sA[cur][(wm * 64 + mi * 16 + l15) * 32 + lhi * 8];
#pragma unroll
        for (int ni = 0; ni < 4; ++ni)
            bf[ni] = *(const s16x8*)&sB[cur][(wn * 64 + ni * 16 + l15) * 32 + lhi * 8];
#pragma unroll
        for (int mi = 0; mi < 4; ++mi)
#pragma unroll
            for (int ni = 0; ni < 4; ++ni)
                acc[mi][ni] = __builtin_amdgcn_mfma_f32_16x16x32_bf16(af[mi], bf[ni], acc[mi][ni], 0, 0, 0);

        __syncthreads();
    }

#pragma unroll
    for (int mi = 0; mi < 4; ++mi)
#pragma unroll
        for (int ni = 0; ni < 4; ++ni)
#pragma unroll
            for (int r = 0; r < 4; ++r)
                Aout[(size_t)(m0 + wm * 64 + mi * 16 + lhi * 4 + r) * DMODEL
                     + n0 + wn * 64 + ni * 16 + l15] = acc[mi][ni][r];
#undef PV_STAGE
}

// ---------------- K7: out = sigmoid((sum_z A_z . wf)/l + b) ----------------
__global__ __launch_bounds__(256) void k_out(const float* __restrict__ apart,
                                             const float* __restrict__ rs_part,
                                             const float* __restrict__ wfw,
                                             const float* __restrict__ wfb,
                                             float* __restrict__ out) {
    int lane = threadIdx.x & 63, w = threadIdx.x >> 6;
    int row = blockIdx.x * 4 + w;
    const float4* wp = (const float4*)(wfw + lane * 8);
    float4 w0 = wp[0], w1 = wp[1];
    float4 a0 = {0.f, 0.f, 0.f, 0.f}, a1 = {0.f, 0.f, 0.f, 0.f};
#pragma unroll
    for (int z = 0; z < 4; ++z) {
        const float4* ap = (const float4*)(apart + (size_t)z * (N_ASSETS * DMODEL) + row * 512 + lane * 8);
        float4 x0 = ap[0], x1 = ap[1];
        a0.x += x0.x; a0.y += x0.y; a0.z += x0.z; a0.w += x0.w;
        a1.x += x1.x; a1.y += x1.y; a1.z += x1.z; a1.w += x1.w;
    }
    float s = a0.x * w0.x + a0.y * w0.y + a0.z * w0.z + a0.w * w0.w
            + a1.x * w1.x + a1.y * w1.y + a1.z * w1.z + a1.w * w1.w;
    float lp = rs_part[lane * N_ASSETS + row];
#pragma unroll
    for (int m = 1; m < 64; m <<= 1) {
        s += __shfl_xor(s, m);
        lp += __shfl_xor(lp, m);
    }
    if (lane == 0) out[row] = 1.f / (1.f + __expf(-(s / lp + wfb[0])));
}

extern "C" void kernel_launch(void* const* d_in, const int* in_sizes, int n_in,
                              void* d_out, int out_size, void* d_ws, size_t ws_size,
                              hipStream_t stream) {
    const float* X    = (const float*)d_in[0];
    const float* rks  = (const float*)d_in[1];
    const float* Wq_w = (const float*)d_in[2];
    const float* Wq_b = (const float*)d_in[3];
    const float* Wk_w = (const float*)d_in[4];
    const float* Wk_b = (const float*)d_in[5];
    const float* Wv_w = (const float*)d_in[6];
    const float* Wv_b = (const float*)d_in[7];
    const float* remb = (const float*)d_in[8];
    const float* wL_w = (const float*)d_in[9];
    const float* wL_b = (const float*)d_in[10];
    const float* wf_w = (const float*)d_in[11];
    const float* wf_b = (const float*)d_in[12];
    float* out = (float*)d_out;
    char* ws = (char*)d_ws;

    const size_t OFF_GATE = 0;                        // 1024 f32
    const size_t OFF_BIAS = 4096;                     // 768 f32 (pad 4KB)
    const size_t OFF_XB   = 8192;                     // 4096x512 bf16 (4MB)
    const size_t OFF_WB   = OFF_XB + 4194304;         // 768x512 bf16 (0.75MB)
    const size_t OFF_QB   = OFF_WB + 786432;          // 4096x128 bf16 (1MB)
    const size_t OFF_KB   = OFF_QB + 1048576;         // 4096x128 bf16 (1MB)
    const size_t OFF_VB   = OFF_KB + 1048576;         // 4096x512 bf16 (4MB)
    const size_t OFF_VT   = OFF_VB + 4194304;         // 512x4096 bf16 (4MB)
    const size_t OFF_A    = OFF_VT + 4194304;         // 4 x 4096x512 f32 (32MB)
    const size_t OFF_P    = OFF_A + 33554432;         // 4096x4096 bf16 (32MB)
    const size_t OFF_RS   = OFF_P + 33554432;         // 64x4096 f32 (1MB)

    float* gate = (float*)(ws + OFF_GATE);
    float* bias = (float*)(ws + OFF_BIAS);
    unsigned short* Xb = (unsigned short*)(ws + OFF_XB);
    unsigned short* Wb = (unsigned short*)(ws + OFF_WB);
    unsigned short* qb = (unsigned short*)(ws + OFF_QB);
    unsigned short* kb = (unsigned short*)(ws + OFF_KB);
    unsigned short* vb = (unsigned short*)(ws + OFF_VB);
    unsigned short* vt = (unsigned short*)(ws + OFF_VT);
    float* apart = (float*)(ws + OFF_A);
    unsigned short* P = (unsigned short*)(ws + OFF_P);
    float* rs_part = (float*)(ws + OFF_RS);

    k_gate<<<4, 256, 0, stream>>>(remb, wL_w, wL_b, gate);
    k_convx<<<2048, 256, 0, stream>>>(X, Xb, N_ASSETS * DMODEL);
    k_convw<<<384, 256, 0, stream>>>(Wq_w, Wk_w, Wv_w, Wq_b, Wk_b, Wv_b, Wb, bias);
    k_qkv<<<dim3(64, 12), 256, 0, stream>>>(Xb, Wb, bias, qb, kb, vb);
    k_transp<<<dim3(64, 8), 256, 0, stream>>>(vb, vt);
    k_score<<<dim3(32, 32), 256, 0, stream>>>(qb, kb, rks, gate, P, rs_part);
    k_pv<<<dim3(32, 4, 4), 256, 0, stream>>>(P, vt, apart);
    k_out<<<1024, 256, 0, stream>>>(apart, rs_part, wf_w, wf_b, out);
}

// Round 4
// 71.705 us; speedup vs baseline: 9.4988x; 1.6102x over previous
//
#include <hip/hip_runtime.h>

#define N_ASSETS 4096
#define DMODEL 512
#define DKQ 128
#define NUM_EMB 1024

typedef float f32x4 __attribute__((ext_vector_type(4)));
typedef short s16x8 __attribute__((ext_vector_type(8)));

__device__ __forceinline__ unsigned short f2bf(float x) {
    unsigned u = __float_as_uint(x);
    u += 0x7FFF + ((u >> 16) & 1);
    return (unsigned short)(u >> 16);
}

__device__ __forceinline__ s16x8 ld8(const unsigned short* p) {
    return *(const s16x8*)p;
}

// ---------------- K_prep: fused small setup work, disjoint block ranges ----------------
// blocks 0..3    : gate[e] = sigmoid(rank_emb[e] @ wL + bL)          (1024 entries)
// blocks 4..131  : Wb[256][512] bf16 = [Wq; Wk], bias[256] = [bq; bk]
// blocks 132..133: weff[din] = sum_dout Wv[dout][din] * wf[dout]     (512 entries)
// block  134     : weff[512] (c slot) = sum_d bv[d] * wf[d]
__global__ __launch_bounds__(256) void k_prep(const float* __restrict__ remb,
                                              const float* __restrict__ wLw,
                                              const float* __restrict__ wLb,
                                              const float* __restrict__ Wq,
                                              const float* __restrict__ Wk,
                                              const float* __restrict__ bq,
                                              const float* __restrict__ bk,
                                              const float* __restrict__ Wv,
                                              const float* __restrict__ bv,
                                              const float* __restrict__ wfw,
                                              float* __restrict__ gate,
                                              unsigned short* __restrict__ Wb,
                                              float* __restrict__ bias,
                                              float* __restrict__ weff) {
    int bid = blockIdx.x;
    int tid = threadIdx.x;
    if (bid < 4) {
        int e = bid * 256 + tid;
        float s = wLb[0];
#pragma unroll
        for (int j = 0; j < 32; ++j) s += remb[e * 32 + j] * wLw[j];
        gate[e] = 1.f / (1.f + __expf(-s));
    } else if (bid < 132) {
        int gid = (bid - 4) * 256 + tid;
        int i4 = gid * 4;
        int row = i4 >> 9;
        int col = i4 & 511;
        const float* src; int r;
        if (row < 128) { src = Wq; r = row; } else { src = Wk; r = row - 128; }
        float4 v = *(const float4*)(src + r * 512 + col);
        ushort4 o;
        o.x = f2bf(v.x); o.y = f2bf(v.y); o.z = f2bf(v.z); o.w = f2bf(v.w);
        *(ushort4*)(Wb + i4) = o;
        if (gid < 256) bias[gid] = (gid < 128) ? bq[gid] : bk[gid - 128];
    } else if (bid < 134) {
        __shared__ float wf_s[512];
        wf_s[tid] = wfw[tid];
        wf_s[tid + 256] = wfw[tid + 256];
        __syncthreads();
        int din = (bid - 132) * 256 + tid;
        float a0 = 0.f, a1 = 0.f, a2 = 0.f, a3 = 0.f;
        for (int dout = 0; dout < 512; dout += 4) {
            a0 += Wv[(dout + 0) * 512 + din] * wf_s[dout + 0];
            a1 += Wv[(dout + 1) * 512 + din] * wf_s[dout + 1];
            a2 += Wv[(dout + 2) * 512 + din] * wf_s[dout + 2];
            a3 += Wv[(dout + 3) * 512 + din] * wf_s[dout + 3];
        }
        weff[din] = (a0 + a1) + (a2 + a3);
    } else {
        // c = bv . wf (one wave is enough; others idle)
        if (tid < 64) {
            float s = 0.f;
#pragma unroll
            for (int j = 0; j < 8; ++j) s += bv[tid * 8 + j] * wfw[tid * 8 + j];
#pragma unroll
            for (int m = 1; m < 64; m <<= 1) s += __shfl_xor(s, m);
            if (tid == 0) weff[512] = s;
        }
    }
}

// ---------------- K1: X fp32 -> bf16 ----------------
__global__ void k_convx(const float* __restrict__ X, unsigned short* __restrict__ Xb, int n) {
    int i4 = (blockIdx.x * 256 + threadIdx.x) * 4;
    if (i4 < n) {
        float4 v = *(const float4*)(X + i4);
        ushort4 o;
        o.x = f2bf(v.x); o.y = f2bf(v.y); o.z = f2bf(v.z); o.w = f2bf(v.w);
        *(ushort4*)(Xb + i4) = o;
    }
}

// ---------------- K2: Q,K projection: C[4096][256] = Xb @ Wb^T + bias ----------------
__global__ __launch_bounds__(256) void k_qk(const unsigned short* __restrict__ Xb,
                                            const unsigned short* __restrict__ Wb,
                                            const float* __restrict__ bias,
                                            unsigned short* __restrict__ qb,
                                            unsigned short* __restrict__ kb) {
    int tid = threadIdx.x;
    int lane = tid & 63, w = tid >> 6;
    int l15 = lane & 15, lhi = lane >> 4;
    int m0 = blockIdx.x * 64 + w * 16;
    int n0 = blockIdx.y * 64;

    f32x4 zero4 = {0.f, 0.f, 0.f, 0.f};
    f32x4 acc[4];
#pragma unroll
    for (int s = 0; s < 4; ++s) acc[s] = zero4;

    const unsigned short* arow = Xb + (m0 + l15) * 512 + lhi * 8;
    for (int k0 = 0; k0 < 512; k0 += 32) {
        s16x8 af = ld8(arow + k0);
#pragma unroll
        for (int s = 0; s < 4; ++s) {
            s16x8 bf = ld8(Wb + (n0 + 16 * s + l15) * 512 + k0 + lhi * 8);
            acc[s] = __builtin_amdgcn_mfma_f32_16x16x32_bf16(af, bf, acc[s], 0, 0, 0);
        }
    }
#pragma unroll
    for (int s = 0; s < 4; ++s) {
        int n = n0 + 16 * s + l15;
        float bv_ = bias[n];
#pragma unroll
        for (int r = 0; r < 4; ++r) {
            int m = m0 + lhi * 4 + r;
            unsigned short val = f2bf(acc[s][r] + bv_);
            if (n < 128) qb[m * 128 + n] = val;
            else         kb[m * 128 + (n - 128)] = val;
        }
    }
}

// ---------------- K3: u[i] = X[i,:] . weff + c  (f32 GEMV) ----------------
__global__ __launch_bounds__(256) void k_ugemv(const float* __restrict__ X,
                                               const float* __restrict__ weff,
                                               float* __restrict__ u) {
    int lane = threadIdx.x & 63, w = threadIdx.x >> 6;
    int row = blockIdx.x * 4 + w;
    const float4* ap = (const float4*)(X + row * 512 + lane * 8);
    const float4* wp = (const float4*)(weff + lane * 8);
    float4 a0 = ap[0], a1 = ap[1], w0 = wp[0], w1 = wp[1];
    float s = a0.x * w0.x + a0.y * w0.y + a0.z * w0.z + a0.w * w0.w
            + a1.x * w1.x + a1.y * w1.y + a1.z * w1.z + a1.w * w1.w;
#pragma unroll
    for (int m = 1; m < 64; m <<= 1) s += __shfl_xor(s, m);
    if (lane == 0) u[row] = s + weff[512];
}

// ---------------- K4: fused score+reduce ----------------
// S = (Q K^T)/sqrt(dk); p = exp(psi*S); accumulate num = sum_j p*u_j, den = sum_j p.
// 128x128 tile, 4 waves (2x2), each wave 64x64 (acc 4x4). Grid (32,32)=1024 blocks.
// Writes 64 deterministic partial slots per row (bn*2+wn).
__global__ __launch_bounds__(256) void k_score(const unsigned short* __restrict__ qb,
                                               const unsigned short* __restrict__ kb,
                                               const float* __restrict__ ranks,
                                               const float* __restrict__ gate,
                                               const float* __restrict__ u,
                                               float* __restrict__ num_part,
                                               float* __restrict__ den_part) {
    __shared__ float g_lds[NUM_EMB];
    __shared__ float rr[128], rc[128], uc[128];
    int tid = threadIdx.x;
    int lane = tid & 63, w = tid >> 6;
    int l15 = lane & 15, lhi = lane >> 4;
    int wm = w >> 1, wn = w & 1;
    int bm = blockIdx.x, bn = blockIdx.y;

    for (int i = tid; i < NUM_EMB; i += 256) g_lds[i] = gate[i];
    if (tid < 128) {
        rr[tid] = ranks[bm * 128 + tid];
        rc[tid] = ranks[bn * 128 + tid];
        uc[tid] = u[bn * 128 + tid];
    }
    __syncthreads();

    int row0 = wm * 64;
    int col0 = wn * 64;

    f32x4 zero4 = {0.f, 0.f, 0.f, 0.f};
    f32x4 acc[4][4];
#pragma unroll
    for (int mi = 0; mi < 4; ++mi)
#pragma unroll
        for (int ni = 0; ni < 4; ++ni) acc[mi][ni] = zero4;

#pragma unroll
    for (int k0 = 0; k0 < DKQ; k0 += 32) {
        s16x8 af[4], bf[4];
#pragma unroll
        for (int mi = 0; mi < 4; ++mi)
            af[mi] = ld8(qb + (bm * 128 + row0 + mi * 16 + l15) * DKQ + k0 + lhi * 8);
#pragma unroll
        for (int ni = 0; ni < 4; ++ni)
            bf[ni] = ld8(kb + (bn * 128 + col0 + ni * 16 + l15) * DKQ + k0 + lhi * 8);
#pragma unroll
        for (int mi = 0; mi < 4; ++mi)
#pragma unroll
            for (int ni = 0; ni < 4; ++ni)
                acc[mi][ni] = __builtin_amdgcn_mfma_f32_16x16x32_bf16(af[mi], bf[ni], acc[mi][ni], 0, 0, 0);
    }

    const float scale = 0.08838834764831845f;  // 1/sqrt(128)
    float num[4][4], den[4][4];
#pragma unroll
    for (int mi = 0; mi < 4; ++mi)
#pragma unroll
        for (int r = 0; r < 4; ++r) { num[mi][r] = 0.f; den[mi][r] = 0.f; }

#pragma unroll
    for (int mi = 0; mi < 4; ++mi) {
#pragma unroll
        for (int ni = 0; ni < 4; ++ni) {
            int coll = col0 + ni * 16 + l15;
            float rj = rc[coll];
            float uj = uc[coll];
#pragma unroll
            for (int r = 0; r < 4; ++r) {
                int rowl = row0 + mi * 16 + lhi * 4 + r;
                float s = acc[mi][ni][r] * scale;
                float diff = fabsf(rr[rowl] - rj);
                int d = min((int)(diff * 0.25f), NUM_EMB - 1);
                float p = __expf(g_lds[d] * s);
                den[mi][r] += p;
                num[mi][r] += p * uj;
            }
        }
    }
#pragma unroll
    for (int mi = 0; mi < 4; ++mi) {
#pragma unroll
        for (int r = 0; r < 4; ++r) {
            float vn = num[mi][r], vd = den[mi][r];
            vn += __shfl_xor(vn, 1); vd += __shfl_xor(vd, 1);
            vn += __shfl_xor(vn, 2); vd += __shfl_xor(vd, 2);
            vn += __shfl_xor(vn, 4); vd += __shfl_xor(vd, 4);
            vn += __shfl_xor(vn, 8); vd += __shfl_xor(vd, 8);
            if (l15 == 0) {
                int row = bm * 128 + row0 + mi * 16 + lhi * 4 + r;
                num_part[(bn * 2 + wn) * N_ASSETS + row] = vn;
                den_part[(bn * 2 + wn) * N_ASSETS + row] = vd;
            }
        }
    }
}

// ---------------- K5: out = sigmoid(num/den + wfb) ----------------
__global__ __launch_bounds__(256) void k_out(const float* __restrict__ num_part,
                                             const float* __restrict__ den_part,
                                             const float* __restrict__ wfb,
                                             float* __restrict__ out) {
    int lane = threadIdx.x & 63, w = threadIdx.x >> 6;
    int row = blockIdx.x * 4 + w;
    float vn = num_part[lane * N_ASSETS + row];
    float vd = den_part[lane * N_ASSETS + row];
#pragma unroll
    for (int m = 1; m < 64; m <<= 1) {
        vn += __shfl_xor(vn, m);
        vd += __shfl_xor(vd, m);
    }
    if (lane == 0) out[row] = 1.f / (1.f + __expf(-(vn / vd + wfb[0])));
}

extern "C" void kernel_launch(void* const* d_in, const int* in_sizes, int n_in,
                              void* d_out, int out_size, void* d_ws, size_t ws_size,
                              hipStream_t stream) {
    const float* X    = (const float*)d_in[0];
    const float* rks  = (const float*)d_in[1];
    const float* Wq_w = (const float*)d_in[2];
    const float* Wq_b = (const float*)d_in[3];
    const float* Wk_w = (const float*)d_in[4];
    const float* Wk_b = (const float*)d_in[5];
    const float* Wv_w = (const float*)d_in[6];
    const float* Wv_b = (const float*)d_in[7];
    const float* remb = (const float*)d_in[8];
    const float* wL_w = (const float*)d_in[9];
    const float* wL_b = (const float*)d_in[10];
    const float* wf_w = (const float*)d_in[11];
    const float* wf_b = (const float*)d_in[12];
    float* out = (float*)d_out;
    char* ws = (char*)d_ws;

    const size_t OFF_GATE = 0;                    // 1024 f32 (4KB)
    const size_t OFF_BIAS = 4096;                 // 256 f32 (pad 4KB)
    const size_t OFF_WEFF = 8192;                 // 513 f32 (pad 4KB)
    const size_t OFF_XB   = 12288;                // 4096x512 bf16 (4MB)
    const size_t OFF_WB   = OFF_XB + 4194304;     // 256x512 bf16 (256KB)
    const size_t OFF_QB   = OFF_WB + 262144;      // 4096x128 bf16 (1MB)
    const size_t OFF_KB   = OFF_QB + 1048576;     // 4096x128 bf16 (1MB)
    const size_t OFF_U    = OFF_KB + 1048576;     // 4096 f32 (16KB)
    const size_t OFF_NUM  = OFF_U + 16384;        // 64x4096 f32 (1MB)
    const size_t OFF_DEN  = OFF_NUM + 1048576;    // 64x4096 f32 (1MB)

    float* gate = (float*)(ws + OFF_GATE);
    float* bias = (float*)(ws + OFF_BIAS);
    float* weff = (float*)(ws + OFF_WEFF);
    unsigned short* Xb = (unsigned short*)(ws + OFF_XB);
    unsigned short* Wb = (unsigned short*)(ws + OFF_WB);
    unsigned short* qb = (unsigned short*)(ws + OFF_QB);
    unsigned short* kb = (unsigned short*)(ws + OFF_KB);
    float* u = (float*)(ws + OFF_U);
    float* num_part = (float*)(ws + OFF_NUM);
    float* den_part = (float*)(ws + OFF_DEN);

    k_prep<<<135, 256, 0, stream>>>(remb, wL_w, wL_b, Wq_w, Wk_w, Wq_b, Wk_b,
                                    Wv_w, Wv_b, wf_w, gate, Wb, bias, weff);
    k_convx<<<2048, 256, 0, stream>>>(X, Xb, N_ASSETS * DMODEL);
    k_qk<<<dim3(64, 4), 256, 0, stream>>>(Xb, Wb, bias, qb, kb);
    k_ugemv<<<1024, 256, 0, stream>>>(X, weff, u);
    k_score<<<dim3(32, 32), 256, 0, stream>>>(qb, kb, rks, gate, u, num_part, den_part);
    k_out<<<1024, 256, 0, stream>>>(num_part, den_part, wf_b, out);
}